// Round 3
// baseline (3322.746 us; speedup 1.0000x reference)
//
#include <hip/hip_runtime.h>
#include <hip/hip_bf16.h>

namespace {

typedef __attribute__((ext_vector_type(8))) short short8x;
typedef __attribute__((ext_vector_type(4))) float f32x4;

__device__ __forceinline__ float bf2f(unsigned short h) {
    return __uint_as_float(((unsigned int)h) << 16);
}
__device__ __forceinline__ unsigned short f2bf(float f) {
    __hip_bfloat16 h = __float2bfloat16(f);
    return *reinterpret_cast<unsigned short*>(&h);
}

enum { ACT_NONE = 0, ACT_TANH = 1 };
enum { EPI_NONE = 0, EPI_KSCALE = 1, EPI_ADDVEC = 2 };

// ---------------- bf16 MFMA GEMM: C[m,n] = sum_k A[m,k]*B[n,k] -----------------
template <int ACT, int EPI, int SBF>
__launch_bounds__(256) __global__
void gemm_mfma(int Npad, int K, int Nreal, int Cstride,
               const unsigned short* __restrict__ A,
               const unsigned short* __restrict__ B,
               float* __restrict__ Cf, unsigned short* __restrict__ Cb,
               const float* __restrict__ epi)
{
    __shared__ unsigned short as_[128 * 32];
    __shared__ unsigned short bs_[128 * 32];
    const int tid = threadIdx.x;
    const int lane = tid & 63;
    const int wave = tid >> 6;
    const int m0 = blockIdx.y << 7;
    const int n0 = blockIdx.x << 7;
    const int wm = (wave >> 1) << 6;
    const int wn = (wave & 1) << 6;

    f32x4 acc[4][4];
    const f32x4 zero = {0.f, 0.f, 0.f, 0.f};
#pragma unroll
    for (int i = 0; i < 4; ++i)
#pragma unroll
        for (int j = 0; j < 4; ++j) acc[i][j] = zero;

    const int sr = tid >> 2;
    const int sc4 = tid & 3;

    for (int k0 = 0; k0 < K; k0 += 32) {
        const uint4 a0 = *(const uint4*)(A + (size_t)(m0 + sr) * K + k0 + sc4 * 8);
        const uint4 a1 = *(const uint4*)(A + (size_t)(m0 + 64 + sr) * K + k0 + sc4 * 8);
        const uint4 b0 = *(const uint4*)(B + (size_t)(n0 + sr) * K + k0 + sc4 * 8);
        const uint4 b1 = *(const uint4*)(B + (size_t)(n0 + 64 + sr) * K + k0 + sc4 * 8);
        __syncthreads();
        {
            int r = sr, p = sc4 ^ ((r >> 1) & 3);
            *(uint4*)&as_[r * 32 + p * 8] = a0;
            *(uint4*)&bs_[r * 32 + p * 8] = b0;
            r = 64 + sr; p = sc4 ^ ((r >> 1) & 3);
            *(uint4*)&as_[r * 32 + p * 8] = a1;
            *(uint4*)&bs_[r * 32 + p * 8] = b1;
        }
        __syncthreads();
        const int q = lane >> 4;
        const int l15 = lane & 15;
        short8x af[4], bfr[4];
#pragma unroll
        for (int i = 0; i < 4; ++i) {
            const int m = wm + (i << 4) + l15;
            const int pa = q ^ ((m >> 1) & 3);
            af[i] = *(const short8x*)&as_[m * 32 + pa * 8];
            const int n = wn + (i << 4) + l15;
            const int pb = q ^ ((n >> 1) & 3);
            bfr[i] = *(const short8x*)&bs_[n * 32 + pb * 8];
        }
#pragma unroll
        for (int i = 0; i < 4; ++i)
#pragma unroll
            for (int j = 0; j < 4; ++j)
                acc[i][j] = __builtin_amdgcn_mfma_f32_16x16x32_bf16(af[i], bfr[j], acc[i][j], 0, 0, 0);
    }

    const int q = lane >> 4;
    const int cn = lane & 15;
#pragma unroll
    for (int i = 0; i < 4; ++i) {
#pragma unroll
        for (int j = 0; j < 4; ++j) {
#pragma unroll
            for (int rr = 0; rr < 4; ++rr) {
                const int row = m0 + wm + (i << 4) + (q << 2) + rr;
                const int col = n0 + wn + (j << 4) + cn;
                if (col >= Nreal) continue;
                float v = acc[i][j][rr];
                if constexpr (ACT == ACT_TANH) v = tanhf(v);
                if constexpr (EPI == EPI_KSCALE)
                    v *= __expf(fminf(epi[(size_t)row * 1024 + col], 0.f));
                if constexpr (EPI == EPI_ADDVEC) v += epi[col];
                if constexpr (SBF) Cb[(size_t)row * Cstride + col] = f2bf(v);
                else               Cf[(size_t)row * Cstride + col] = v;
            }
        }
    }
}

__launch_bounds__(256) __global__
void mix_k(const float* __restrict__ x, const float* __restrict__ xla,
           const float* __restrict__ mux, unsigned short* __restrict__ out)
{
    const size_t idx = ((size_t)blockIdx.x * 256 + threadIdx.x) * 4;
    const int c = (int)(idx & 1023);
    const float4 xv = *(const float4*)(x + idx);
    const float4 xl = *(const float4*)(xla + idx);
    const float4 mu = *(const float4*)(mux + c);
    ushort4 o;
    o.x = f2bf(xv.x + (xl.x - xv.x) * mu.x);
    o.y = f2bf(xv.y + (xl.y - xv.y) * mu.y);
    o.z = f2bf(xv.z + (xl.z - xv.z) * mu.z);
    o.w = f2bf(xv.w + (xl.w - xv.w) * mu.w);
    *(ushort4*)(out + idx) = o;
}

__launch_bounds__(256) __global__
void convert_k(const float* __restrict__ src, unsigned short* __restrict__ dst)
{
    const size_t idx = ((size_t)blockIdx.x * 256 + threadIdx.x) * 4;
    const float4 v = *(const float4*)(src + idx);
    ushort4 o;
    o.x = f2bf(v.x); o.y = f2bf(v.y); o.z = f2bf(v.z); o.w = f2bf(v.w);
    *(ushort4*)(dst + idx) = o;
}

__launch_bounds__(256) __global__
void transpose_k(const float* __restrict__ src, unsigned short* __restrict__ dst,
                 int K, int Nsrc)
{
    const int k = blockIdx.x * 256 + threadIdx.x;
    const int n = blockIdx.y;
    if (k < K)
        dst[(size_t)n * K + k] = (n < Nsrc) ? f2bf(src[(size_t)k * Nsrc + n]) : (unsigned short)0;
}

__launch_bounds__(256) __global__
void xdd_k(const float* __restrict__ x, const float* __restrict__ xla,
           const unsigned short* __restrict__ t1, const float* __restrict__ blora,
           const float* __restrict__ lam, unsigned short* __restrict__ out, int f)
{
    __shared__ float sh[4][32];
    const int tid = threadIdx.x;
    const int m0 = blockIdx.x << 2;
    if (tid < 128) {
        const int r = tid >> 5, kk = tid & 31;
        sh[r][kk] = bf2f(t1[(size_t)f * 524288 + (size_t)(m0 + r) * 32 + kk]);
    }
    __syncthreads();
    const int c0 = tid << 2;
    const float* bl = blora + f * 32768 + c0;
    float dot[4][4];
#pragma unroll
    for (int r = 0; r < 4; ++r)
#pragma unroll
        for (int j = 0; j < 4; ++j) dot[r][j] = 0.f;
    for (int kk = 0; kk < 32; ++kk) {
        const float4 b4 = *(const float4*)(bl + (size_t)kk * 1024);
#pragma unroll
        for (int r = 0; r < 4; ++r) {
            const float tv = sh[r][kk];
            dot[r][0] = fmaf(tv, b4.x, dot[r][0]);
            dot[r][1] = fmaf(tv, b4.y, dot[r][1]);
            dot[r][2] = fmaf(tv, b4.z, dot[r][2]);
            dot[r][3] = fmaf(tv, b4.w, dot[r][3]);
        }
    }
    const float4 l4 = *(const float4*)(lam + f * 1024 + c0);
#pragma unroll
    for (int r = 0; r < 4; ++r) {
        const size_t idx = (size_t)(m0 + r) * 1024 + c0;
        const float4 xv = *(const float4*)(x + idx);
        const float4 xl = *(const float4*)(xla + idx);
        ushort4 o;
        o.x = f2bf(xv.x + (xl.x - xv.x) * (l4.x + dot[r][0]));
        o.y = f2bf(xv.y + (xl.y - xv.y) * (l4.y + dot[r][1]));
        o.z = f2bf(xv.z + (xl.z - xv.z) * (l4.z + dot[r][2]));
        o.w = f2bf(xv.w + (xl.w - xv.w) * (l4.w + dot[r][3]));
        *(ushort4*)(out + idx) = o;
    }
}

// ======================= chunked WKV6 (L=64, 32 chunks/head) =======================
// Layouts: SU[g][i][j] bf16 (g = bh*32+c, i = value col, j = key row);
//          Abuf[g][j] fp32 = per-channel decay product over chunk g.

// Pass A: per-chunk local state U (from zero) + decay products. 4096 blocks x 1 wave.
#define CS_PROC(KK, VV, WW)                                                   \
    do {                                                                      \
        _Pragma("unroll")                                                     \
        for (int tt = 0; tt < 8; ++tt) {                                      \
            const float ki = bf2f(KK[tt]);                                    \
            const float vi = bf2f(VV[tt]);                                    \
            const float di = __expf(-__expf(WW[tt]));                         \
            kd[i] = make_float2(ki, di);                                      \
            __builtin_amdgcn_wave_barrier();                                  \
            aprod *= di;                                                      \
            _Pragma("unroll")                                                 \
            for (int jj = 0; jj < 64; jj += 2) {                              \
                const float4 t4 = *(const float4*)&kd[jj];                    \
                s[jj]     = fmaf(t4.y, s[jj],     t4.x * vi);                 \
                s[jj + 1] = fmaf(t4.w, s[jj + 1], t4.z * vi);                 \
            }                                                                 \
            __builtin_amdgcn_wave_barrier();                                  \
        }                                                                     \
    } while (0)

__launch_bounds__(64) __global__
void wkv_chunkstate_k(const unsigned short* __restrict__ k, const unsigned short* __restrict__ v,
                      const float* __restrict__ w, unsigned short* __restrict__ SU,
                      float* __restrict__ Abuf)
{
    const int g = blockIdx.x;
    const int bh = g >> 5;
    const int b = bh >> 4, h = bh & 15;
    const int t0 = (g & 31) << 6;
    const int i = threadIdx.x;
    const size_t base = ((size_t)b * 2048 + t0) * 1024 + (h << 6) + i;

    float s[64];
#pragma unroll
    for (int j = 0; j < 64; ++j) s[j] = 0.f;
    float aprod = 1.f;
    __shared__ float2 kd[64];

    unsigned short ka[8], va[8]; float wa[8];
    unsigned short kb[8], vb[8]; float wb[8];
#pragma unroll
    for (int tt = 0; tt < 8; ++tt) {
        const size_t id = base + (size_t)tt * 1024;
        ka[tt] = k[id]; va[tt] = v[id]; wa[tt] = w[id];
    }
    for (int c = 0; c < 8; c += 2) {
        {
            const size_t cb_ = base + (size_t)(c + 1) * 8192;
#pragma unroll
            for (int tt = 0; tt < 8; ++tt) {
                const size_t id = cb_ + (size_t)tt * 1024;
                kb[tt] = k[id]; vb[tt] = v[id]; wb[tt] = w[id];
            }
        }
        CS_PROC(ka, va, wa);
        if (c + 2 < 8) {
            const size_t ca_ = base + (size_t)(c + 2) * 8192;
#pragma unroll
            for (int tt = 0; tt < 8; ++tt) {
                const size_t id = ca_ + (size_t)tt * 1024;
                ka[tt] = k[id]; va[tt] = v[id]; wa[tt] = w[id];
            }
        }
        CS_PROC(kb, vb, wb);
    }

    unsigned short* up = SU + (size_t)g * 4096 + i * 64;
#pragma unroll
    for (int jj = 0; jj < 64; jj += 4) {
        ushort4 o;
        o.x = f2bf(s[jj]); o.y = f2bf(s[jj + 1]);
        o.z = f2bf(s[jj + 2]); o.w = f2bf(s[jj + 3]);
        *(ushort4*)(up + jj) = o;
    }
    Abuf[(size_t)g * 64 + i] = aprod;
}

// Pass B: sequential chunk-state propagation; writes chunk-start S_c in place of U_c.
__launch_bounds__(64) __global__
void wkv_stateprop_k(const float* __restrict__ s_in, unsigned short* __restrict__ SU,
                     const float* __restrict__ Abuf, float* __restrict__ s_out)
{
    const int bh = blockIdx.x;
    const int i = threadIdx.x;
    float s[64];
#pragma unroll
    for (int j = 0; j < 64; ++j) s[j] = s_in[(size_t)bh * 4096 + j * 64 + i];

    for (int c = 0; c < 32; ++c) {
        const int g = (bh << 5) + c;
        unsigned short* up = SU + (size_t)g * 4096 + i * 64;
        ushort4 uv[16];
#pragma unroll
        for (int q = 0; q < 16; ++q) uv[q] = *(const ushort4*)(up + q * 4);
#pragma unroll
        for (int jj = 0; jj < 64; jj += 4) {
            ushort4 o;
            o.x = f2bf(s[jj]); o.y = f2bf(s[jj + 1]);
            o.z = f2bf(s[jj + 2]); o.w = f2bf(s[jj + 3]);
            *(ushort4*)(up + jj) = o;
        }
#pragma unroll
        for (int jj = 0; jj < 64; jj += 4) {
            const float4 a4 = *(const float4*)(Abuf + (size_t)g * 64 + jj);
            const ushort4 uq = uv[jj >> 2];
            s[jj]     = fmaf(a4.x, s[jj],     bf2f(uq.x));
            s[jj + 1] = fmaf(a4.y, s[jj + 1], bf2f(uq.y));
            s[jj + 2] = fmaf(a4.z, s[jj + 2], bf2f(uq.z));
            s[jj + 3] = fmaf(a4.w, s[jj + 3], bf2f(uq.w));
        }
    }
#pragma unroll
    for (int j = 0; j < 64; ++j) s_out[(size_t)bh * 4096 + j * 64 + i] = s[j];
}

// Pass C: per-chunk scan from stored chunk-start state; writes y. 4096 blocks x 1 wave.
__launch_bounds__(64) __global__
void wkv_scan_k(const unsigned short* __restrict__ r, const unsigned short* __restrict__ k,
                const unsigned short* __restrict__ v, const float* __restrict__ w,
                const float* __restrict__ u, const unsigned short* __restrict__ SU,
                float* __restrict__ y)
{
    const int g = blockIdx.x;
    const int bh = g >> 5;
    const int b = bh >> 4, h = bh & 15;
    const int t0 = (g & 31) << 6;
    const int i = threadIdx.x;
    const size_t base = ((size_t)b * 2048 + t0) * 1024 + (h << 6) + i;
    const float ui = u[(h << 6) + i];

    float s[64];
    {
        const unsigned short* sp = SU + (size_t)g * 4096 + i * 64;
#pragma unroll
        for (int jj = 0; jj < 64; jj += 4) {
            const ushort4 q4 = *(const ushort4*)(sp + jj);
            s[jj] = bf2f(q4.x); s[jj + 1] = bf2f(q4.y);
            s[jj + 2] = bf2f(q4.z); s[jj + 3] = bf2f(q4.w);
        }
    }
    __shared__ float4 sh[64];
    for (int cg = 0; cg < 8; ++cg) {
        unsigned short ra[8], ka[8], va[8]; float wa[8];
#pragma unroll
        for (int tt = 0; tt < 8; ++tt) {
            const size_t id = base + (size_t)(cg * 8 + tt) * 1024;
            ra[tt] = r[id]; ka[tt] = k[id]; va[tt] = v[id]; wa[tt] = w[id];
        }
#pragma unroll
        for (int tt = 0; tt < 8; ++tt) {
            const float ri = bf2f(ra[tt]);
            const float ki = bf2f(ka[tt]);
            const float vi = bf2f(va[tt]);
            const float di = __expf(-__expf(wa[tt]));
            sh[i] = make_float4(ri, ki, di, ri * ki * ui);
            __builtin_amdgcn_wave_barrier();
            float yv = 0.f;
#pragma unroll
            for (int jj = 0; jj < 64; ++jj) {
                const float4 t4 = sh[jj];
                const float sj = s[jj];
                yv = fmaf(t4.x, sj, yv);
                yv = fmaf(t4.w, vi, yv);
                s[jj] = fmaf(t4.z, sj, t4.y * vi);
            }
            y[base + (size_t)(cg * 8 + tt) * 1024] = yv;
            __builtin_amdgcn_wave_barrier();
        }
    }
}

// GroupNorm over heads of 64 ch (eps = 1e-5*16), then *g, store bf16 z.
__launch_bounds__(256) __global__
void gn_k(const float* __restrict__ y, const unsigned short* __restrict__ g,
          const float* __restrict__ gam, const float* __restrict__ bet,
          unsigned short* __restrict__ z)
{
    const int tid = threadIdx.x;
    const size_t row = blockIdx.x;
    const int c0 = tid << 2;
    const size_t idx = row * 1024 + c0;
    const float4 a = *(const float4*)(y + idx);
    const float yv0 = a.x, yv1 = a.y, yv2 = a.z, yv3 = a.w;
    float sm = yv0 + yv1 + yv2 + yv3;
    float q = yv0 * yv0 + yv1 * yv1 + yv2 * yv2 + yv3 * yv3;
#pragma unroll
    for (int off = 1; off < 16; off <<= 1) {
        sm += __shfl_xor(sm, off, 64);
        q += __shfl_xor(q, off, 64);
    }
    const float mean = sm * (1.f / 64.f);
    const float var = q * (1.f / 64.f) - mean * mean;
    const float rstd = rsqrtf(var + 1.6e-4f);
    const float4 gm = *(const float4*)(gam + c0);
    const float4 bt = *(const float4*)(bet + c0);
    const ushort4 gg = *(const ushort4*)(g + idx);
    ushort4 o;
    o.x = f2bf(((yv0 - mean) * rstd * gm.x + bt.x) * bf2f(gg.x));
    o.y = f2bf(((yv1 - mean) * rstd * gm.y + bt.y) * bf2f(gg.y));
    o.z = f2bf(((yv2 - mean) * rstd * gm.z + bt.z) * bf2f(gg.z));
    o.w = f2bf(((yv3 - mean) * rstd * gm.w + bt.w) * bf2f(gg.w));
    *(ushort4*)(z + idx) = o;
}

__launch_bounds__(256) __global__
void copy_k(const float4* __restrict__ src, float4* __restrict__ dst)
{
    const size_t i = (size_t)blockIdx.x * 256 + threadIdx.x;
    dst[i] = src[i];
}

}  // namespace

extern "C" void kernel_launch(void* const* d_in, const int* in_sizes, int n_in,
                              void* d_out, int out_size, void* d_ws, size_t ws_size,
                              hipStream_t stream)
{
    (void)in_sizes; (void)n_in; (void)out_size; (void)ws_size;
    const float* x     = (const float*)d_in[0];
    const float* xla   = (const float*)d_in[1];
    const float* s_in  = (const float*)d_in[2];
    const float* mux   = (const float*)d_in[3];
    const float* lam   = (const float*)d_in[4];
    const float* Amat  = (const float*)d_in[5];
    const float* blora = (const float*)d_in[6];
    const float* tdmu  = (const float*)d_in[7];
    const float* tdA   = (const float*)d_in[8];
    const float* tdB   = (const float*)d_in[9];
    const float* u     = (const float*)d_in[10];
    const float* Wk    = (const float*)d_in[11];
    const float* Wv    = (const float*)d_in[12];
    const float* Wr    = (const float*)d_in[13];
    const float* Wo    = (const float*)d_in[14];
    const float* Wg1   = (const float*)d_in[15];
    const float* Wg2   = (const float*)d_in[16];
    const float* gam   = (const float*)d_in[17];
    const float* bet   = (const float*)d_in[18];

    float* out  = (float*)d_out;          // w-scratch until final GEMM
    float* xraw = out + 16777216;         // y scratch until final copy
    float* snew = out + 2 * 16777216;

    char* ws = (char*)d_ws;
    unsigned short* mixb   = (unsigned short*)(ws);              // 32 MB (dead after G1 -> SU)
    unsigned short* xddb   = (unsigned short*)(ws + 33554432);   // 32 MB (dead after f=4 -> Abuf)
    unsigned short* t1     = (unsigned short*)(ws + 67108864);   // 5.25 MB
    unsigned short* tanh64 = (unsigned short*)(ws + 72351744);   // 2 MB
    unsigned short* tanhg  = (unsigned short*)(ws + 74448896);   // 5.25 MB
    unsigned short* kbuf   = (unsigned short*)(ws + 79691776);   // 32 MB (-> z after wkv)
    unsigned short* vbuf   = (unsigned short*)(ws + 113246208);  // 32 MB
    unsigned short* rbuf   = (unsigned short*)(ws + 146800640);  // 32 MB
    unsigned short* gbuf   = (unsigned short*)(ws + 180355072);  // 32 MB
    unsigned short* wkt    = (unsigned short*)(ws + 213909504);  // 2 MB
    unsigned short* wvt    = (unsigned short*)(ws + 216006656);
    unsigned short* wrt    = (unsigned short*)(ws + 218103808);
    unsigned short* wot    = (unsigned short*)(ws + 220200960);
    unsigned short* at_    = (unsigned short*)(ws + 222298112);
    unsigned short* tdat   = (unsigned short*)(ws + 222822400);
    unsigned short* tdbt   = (unsigned short*)(ws + 223084544);
    unsigned short* wg1t   = (unsigned short*)(ws + 223215616);
    unsigned short* wg2t   = (unsigned short*)(ws + 223739904);  // end ~224 MB

    float* w  = out;                              // 16384x1024 fp32
    float* y  = xraw;                             // fp32 y
    unsigned short* SU = mixb;                    // 4096 x 4096 bf16 (32 MB)
    float* Abuf = (float*)xddb;                   // 4096 x 64 fp32 (1 MB)

    // --- weight conversions ---
    convert_k<<<1024, 256, 0, stream>>>(Wk, wkt);
    convert_k<<<1024, 256, 0, stream>>>(Wv, wvt);
    convert_k<<<1024, 256, 0, stream>>>(Wr, wrt);
    convert_k<<<1024, 256, 0, stream>>>(Wo, wot);
    transpose_k<<<dim3(4, 256), 256, 0, stream>>>(Amat, at_, 1024, 160);
    transpose_k<<<dim3(4, 128), 256, 0, stream>>>(tdA, tdat, 1024, 64);
    transpose_k<<<dim3(1, 1024), 256, 0, stream>>>(tdB, tdbt, 64, 1024);
    transpose_k<<<dim3(4, 256), 256, 0, stream>>>(Wg1, wg1t, 1024, 160);
    transpose_k<<<dim3(1, 1024), 256, 0, stream>>>(Wg2, wg2t, 160, 1024);

    // --- G1: t1 = tanh(mix @ A) ---
    mix_k<<<16384, 256, 0, stream>>>(x, xla, mux, mixb);
    gemm_mfma<ACT_TANH, EPI_NONE, 1><<<dim3(2, 128), 256, 0, stream>>>(
        256, 1024, 160, 160, mixb, at_, nullptr, t1, nullptr);

    // --- f=0: w = tdmu + tanh(w0 @ tdA) @ tdB ---
    xdd_k<<<4096, 256, 0, stream>>>(x, xla, t1, blora, lam, xddb, 0);
    gemm_mfma<ACT_TANH, EPI_NONE, 1><<<dim3(1, 128), 256, 0, stream>>>(
        128, 1024, 64, 64, xddb, tdat, nullptr, tanh64, nullptr);
    gemm_mfma<ACT_NONE, EPI_ADDVEC, 0><<<dim3(8, 128), 256, 0, stream>>>(
        1024, 64, 1024, 1024, tanh64, tdbt, w, nullptr, tdmu);

    // --- f=1: k = (k0 @ Wk^T) * exp(min(w,0)) -> bf16 ---
    xdd_k<<<4096, 256, 0, stream>>>(x, xla, t1, blora, lam, xddb, 1);
    gemm_mfma<ACT_NONE, EPI_KSCALE, 1><<<dim3(8, 128), 256, 0, stream>>>(
        1024, 1024, 1024, 1024, xddb, wkt, nullptr, kbuf, w);

    // --- f=2: v ---
    xdd_k<<<4096, 256, 0, stream>>>(x, xla, t1, blora, lam, xddb, 2);
    gemm_mfma<ACT_NONE, EPI_NONE, 1><<<dim3(8, 128), 256, 0, stream>>>(
        1024, 1024, 1024, 1024, xddb, wvt, nullptr, vbuf, nullptr);

    // --- f=3: r ---
    xdd_k<<<4096, 256, 0, stream>>>(x, xla, t1, blora, lam, xddb, 3);
    gemm_mfma<ACT_NONE, EPI_NONE, 1><<<dim3(8, 128), 256, 0, stream>>>(
        1024, 1024, 1024, 1024, xddb, wrt, nullptr, rbuf, nullptr);

    // --- f=4: g = tanh(g0 @ Wg1) @ Wg2 ---
    xdd_k<<<4096, 256, 0, stream>>>(x, xla, t1, blora, lam, xddb, 4);
    gemm_mfma<ACT_TANH, EPI_NONE, 1><<<dim3(2, 128), 256, 0, stream>>>(
        256, 1024, 160, 160, xddb, wg1t, nullptr, tanhg, nullptr);
    gemm_mfma<ACT_NONE, EPI_NONE, 1><<<dim3(8, 128), 256, 0, stream>>>(
        1024, 160, 1024, 1024, tanhg, wg2t, nullptr, gbuf, nullptr);

    // --- chunked WKV scan ---
    wkv_chunkstate_k<<<4096, 64, 0, stream>>>(kbuf, vbuf, w, SU, Abuf);
    wkv_stateprop_k<<<128, 64, 0, stream>>>(s_in, SU, Abuf, snew);
    wkv_scan_k<<<4096, 64, 0, stream>>>(rbuf, kbuf, vbuf, w, u, SU, y);

    // --- GroupNorm(y)*g -> z (reuses kbuf) ---
    gn_k<<<16384, 256, 0, stream>>>(y, gbuf, gam, bet, kbuf);

    // --- out = z @ Wo^T ---
    gemm_mfma<ACT_NONE, EPI_NONE, 0><<<dim3(8, 128), 256, 0, stream>>>(
        1024, 1024, 1024, 1024, kbuf, wot, out, nullptr, nullptr);

    // --- x_raw = x ---
    copy_k<<<16384, 256, 0, stream>>>((const float4*)x, (float4*)xraw);
}